// Round 1
// baseline (1224.981 us; speedup 1.0000x reference)
//
#include <hip/hip_runtime.h>
#include <hip/hip_bf16.h>

namespace {
constexpr int kB = 4;
constexpr int kC = 512;
constexpr int kH = 128;
constexpr int kW = 128;
constexpr int kCQK = 64;
constexpr int kL = kH * kW;   // 16384
constexpr int kO = 640;       // rows: [0,64)=Wq, [64,128)=Wk, [128,640)=Wv

// workspace layout (float offsets)
constexpr size_t OFF_WALL = 0;                          // 640*512
constexpr size_t OFF_BALL = (size_t)kO * kC;            // 640
constexpr size_t OFF_QKV  = OFF_BALL + kO;              // B*640*L
constexpr size_t OFF_E    = OFF_QKV + (size_t)kB * kO * kL;  // B*H*W*256
constexpr size_t WS_FLOATS = OFF_E + (size_t)kB * kH * kW * 256;
}

// ---------------- pack W/bias into one (640 x 512) matrix ----------------
__global__ __launch_bounds__(256) void pack_w(
    const float* __restrict__ Wq, const float* __restrict__ bq,
    const float* __restrict__ Wk, const float* __restrict__ bk,
    const float* __restrict__ Wv, const float* __restrict__ bv,
    float* __restrict__ Wall, float* __restrict__ ball) {
  const int r = blockIdx.x;      // 0..639
  const int t = threadIdx.x;     // 256
  const float* src;
  if (r < 64) {
    src = Wq + (size_t)r * kC;
    if (t == 0) ball[r] = bq[r];
  } else if (r < 128) {
    src = Wk + (size_t)(r - 64) * kC;
    if (t == 0) ball[r] = bk[r - 64];
  } else {
    src = Wv + (size_t)(r - 128) * kC;
    if (t == 0) ball[r] = bv[r - 128];
  }
  Wall[(size_t)r * kC + t] = src[t];
  Wall[(size_t)r * kC + 256 + t] = src[256 + t];
}

// ---------------- projection GEMM: qkv[b][o][l] = sum_c Wall[o][c]*x[b][c][l] + ball[o] ----
// BM=128, BN=128, BK=32, 256 threads, 8x8 micro-tile
__global__ __launch_bounds__(256) void proj_gemm(
    const float* __restrict__ x, const float* __restrict__ Wall,
    const float* __restrict__ ball, float* __restrict__ qkv) {
  __shared__ float sW[32][128];   // [k][m]
  __shared__ float sX[32][128];   // [k][n]
  const int b  = blockIdx.z;
  const int m0 = blockIdx.y * 128;
  const int n0 = blockIdx.x * 128;
  const float* Xb = x + (size_t)b * kC * kL;
  const int t  = threadIdx.x;
  const int tx = t & 15, ty = t >> 4;
  float acc[8][8];
#pragma unroll
  for (int i = 0; i < 8; ++i)
#pragma unroll
    for (int j = 0; j < 8; ++j) acc[i][j] = 0.f;

  for (int k0 = 0; k0 < kC; k0 += 32) {
    // stage W tile (transposed): thread -> row m=t>>1, 16 floats at kh=(t&1)*16
    {
      const int m = t >> 1, kh = (t & 1) * 16;
      const float* src = Wall + (size_t)(m0 + m) * kC + k0 + kh;
      float tmp[16];
      *(float4*)(tmp + 0)  = *(const float4*)(src + 0);
      *(float4*)(tmp + 4)  = *(const float4*)(src + 4);
      *(float4*)(tmp + 8)  = *(const float4*)(src + 8);
      *(float4*)(tmp + 12) = *(const float4*)(src + 12);
#pragma unroll
      for (int r = 0; r < 16; ++r) sW[kh + r][m] = tmp[r];
    }
    // stage X tile
#pragma unroll
    for (int p = 0; p < 4; ++p) {
      const int idx = p * 256 + t;
      const int cc = idx >> 5, l4 = (idx & 31) * 4;
      *(float4*)&sX[cc][l4] =
          *(const float4*)(Xb + (size_t)(k0 + cc) * kL + n0 + l4);
    }
    __syncthreads();
#pragma unroll
    for (int kk = 0; kk < 32; ++kk) {
      float a[8], bb[8];
      *(float4*)(a + 0) = *(const float4*)&sW[kk][ty * 8];
      *(float4*)(a + 4) = *(const float4*)&sW[kk][ty * 8 + 4];
      *(float4*)(bb + 0) = *(const float4*)&sX[kk][tx * 8];
      *(float4*)(bb + 4) = *(const float4*)&sX[kk][tx * 8 + 4];
#pragma unroll
      for (int i = 0; i < 8; ++i)
#pragma unroll
        for (int j = 0; j < 8; ++j) acc[i][j] = fmaf(a[i], bb[j], acc[i][j]);
    }
    __syncthreads();
  }
#pragma unroll
  for (int i = 0; i < 8; ++i) {
    const int m = m0 + ty * 8 + i;
    const float bias = ball[m];
    float* dst = qkv + ((size_t)b * kO + m) * kL + n0 + tx * 8;
    float4 o0 = {acc[i][0] + bias, acc[i][1] + bias, acc[i][2] + bias, acc[i][3] + bias};
    float4 o1 = {acc[i][4] + bias, acc[i][5] + bias, acc[i][6] + bias, acc[i][7] + bias};
    *(float4*)(dst + 0) = o0;
    *(float4*)(dst + 4) = o1;
  }
}

// ---------------- e_row: e[b][h][w][i] = sum_c q[b,c,h,w] * k[b,c,h,i] ----------------
// one block per (b,h); output tile (w rows, i cols)
__global__ __launch_bounds__(256) void erow_kernel(
    const float* __restrict__ qkv, float* __restrict__ e) {
  __shared__ float sQ[32][128];   // [c][w]
  __shared__ float sK[32][128];   // [c][i]
  const int bh = blockIdx.x;
  const int b = bh >> 7, h = bh & 127;
  const int t = threadIdx.x;
  const int tx = t & 15, ty = t >> 4;
  float acc[8][8];
#pragma unroll
  for (int i = 0; i < 8; ++i)
#pragma unroll
    for (int j = 0; j < 8; ++j) acc[i][j] = 0.f;

  for (int k0 = 0; k0 < kCQK; k0 += 32) {
#pragma unroll
    for (int p = 0; p < 4; ++p) {
      const int idx = p * 256 + t;
      const int cc = idx >> 5, w4 = (idx & 31) * 4;
      const size_t base = ((size_t)b * kO + k0 + cc) * kL + h * kW + w4;
      *(float4*)&sQ[cc][w4] = *(const float4*)(qkv + base);
      *(float4*)&sK[cc][w4] = *(const float4*)(qkv + base + (size_t)64 * kL);
    }
    __syncthreads();
#pragma unroll
    for (int kk = 0; kk < 32; ++kk) {
      float a[8], bb[8];
      *(float4*)(a + 0) = *(const float4*)&sQ[kk][ty * 8];
      *(float4*)(a + 4) = *(const float4*)&sQ[kk][ty * 8 + 4];
      *(float4*)(bb + 0) = *(const float4*)&sK[kk][tx * 8];
      *(float4*)(bb + 4) = *(const float4*)&sK[kk][tx * 8 + 4];
#pragma unroll
      for (int wi = 0; wi < 8; ++wi)
#pragma unroll
        for (int ii = 0; ii < 8; ++ii) acc[wi][ii] = fmaf(a[wi], bb[ii], acc[wi][ii]);
    }
    __syncthreads();
  }
#pragma unroll
  for (int wi = 0; wi < 8; ++wi) {
    const int w = ty * 8 + wi;
    float* dst = e + (((size_t)b * kH + h) * kW + w) * 256 + tx * 8;
    float4 o0 = {acc[wi][0], acc[wi][1], acc[wi][2], acc[wi][3]};
    float4 o1 = {acc[wi][4], acc[wi][5], acc[wi][6], acc[wi][7]};
    *(float4*)(dst + 0) = o0;
    *(float4*)(dst + 4) = o1;
  }
}

// ---------------- e_col: e[b][h][w][128+j] = sum_c q[b,c,h,w]*k[b,c,j,w]; diag -> -inf ----
// one block per (b,w); output tile (h rows, j cols)
__global__ __launch_bounds__(256) void ecol_kernel(
    const float* __restrict__ qkv, float* __restrict__ e) {
  __shared__ float sQ[32][128];   // [c][h]
  __shared__ float sK[32][128];   // [c][j]
  const int bw = blockIdx.x;
  const int b = bw >> 7, w = bw & 127;
  const int t = threadIdx.x;
  const int tx = t & 15, ty = t >> 4;
  float acc[8][8];
#pragma unroll
  for (int i = 0; i < 8; ++i)
#pragma unroll
    for (int j = 0; j < 8; ++j) acc[i][j] = 0.f;

  for (int k0 = 0; k0 < kCQK; k0 += 32) {
#pragma unroll
    for (int p = 0; p < 16; ++p) {
      const int idx = p * 256 + t;          // 0..4095
      const int cc = idx >> 7, hh = idx & 127;
      const size_t base = ((size_t)b * kO + k0 + cc) * kL + hh * kW + w;
      sQ[cc][hh] = qkv[base];
      sK[cc][hh] = qkv[base + (size_t)64 * kL];
    }
    __syncthreads();
#pragma unroll
    for (int kk = 0; kk < 32; ++kk) {
      float a[8], bb[8];
      *(float4*)(a + 0) = *(const float4*)&sQ[kk][ty * 8];
      *(float4*)(a + 4) = *(const float4*)&sQ[kk][ty * 8 + 4];
      *(float4*)(bb + 0) = *(const float4*)&sK[kk][tx * 8];
      *(float4*)(bb + 4) = *(const float4*)&sK[kk][tx * 8 + 4];
#pragma unroll
      for (int hi = 0; hi < 8; ++hi)
#pragma unroll
        for (int ji = 0; ji < 8; ++ji) acc[hi][ji] = fmaf(a[hi], bb[ji], acc[hi][ji]);
    }
    __syncthreads();
  }
  const float NEG_INF = __int_as_float(0xff800000);
#pragma unroll
  for (int hi = 0; hi < 8; ++hi) {
    const int h = ty * 8 + hi;
    float vals[8];
#pragma unroll
    for (int ji = 0; ji < 8; ++ji) {
      const int j = tx * 8 + ji;
      vals[ji] = (j == h) ? NEG_INF : acc[hi][ji];
    }
    float* dst = e + (((size_t)b * kH + h) * kW + w) * 256 + 128 + tx * 8;
    float4 o0 = {vals[0], vals[1], vals[2], vals[3]};
    float4 o1 = {vals[4], vals[5], vals[6], vals[7]};
    *(float4*)(dst + 0) = o0;
    *(float4*)(dst + 4) = o1;
  }
}

// ---------------- softmax over the 256 contiguous scores per pixel ----------------
__global__ __launch_bounds__(256) void softmax_kernel(float* __restrict__ e) {
  const int t = threadIdx.x;
  const int wv = t >> 6, lane = t & 63;
  const size_t pix = (size_t)blockIdx.x * 4 + wv;
  float* p = e + pix * 256 + lane * 4;
  float4 v = *(const float4*)p;
  float m = fmaxf(fmaxf(v.x, v.y), fmaxf(v.z, v.w));
#pragma unroll
  for (int off = 32; off > 0; off >>= 1) m = fmaxf(m, __shfl_xor(m, off, 64));
  float e0 = expf(v.x - m), e1 = expf(v.y - m), e2 = expf(v.z - m), e3 = expf(v.w - m);
  float s = e0 + e1 + e2 + e3;
#pragma unroll
  for (int off = 32; off > 0; off >>= 1) s += __shfl_xor(s, off, 64);
  const float inv = 1.0f / s;
  float4 o = {e0 * inv, e1 * inv, e2 * inv, e3 * inv};
  *(float4*)p = o;
}

// ---------------- row aggregation: out[b][c][h][w] = sum_i a_row[i][w] * v[b][c][h][i] ----
// block per (c-tile 128, b*h); 8x8 micro over (c,w)
__global__ __launch_bounds__(256) void rowagg_kernel(
    const float* __restrict__ qkv, const float* __restrict__ e,
    float* __restrict__ out) {
  __shared__ float sV[32][132];   // [i][c] (+4 pad)
  __shared__ float sA[32][132];   // [i][w]
  const int bh = blockIdx.y;
  const int b = bh >> 7, h = bh & 127;
  const int m0 = blockIdx.x * 128;
  const int t = threadIdx.x;
  const int tx = t & 15, ty = t >> 4;
  float acc[8][8];
#pragma unroll
  for (int i = 0; i < 8; ++i)
#pragma unroll
    for (int j = 0; j < 8; ++j) acc[i][j] = 0.f;

  for (int i0 = 0; i0 < kW; i0 += 32) {
    // stage V[c][i] -> sV[i][c]
    {
      const int c = t >> 1, ih = (t & 1) * 16;
      const float* src =
          qkv + ((size_t)b * kO + 128 + m0 + c) * kL + h * kW + i0 + ih;
      float tmp[16];
      *(float4*)(tmp + 0)  = *(const float4*)(src + 0);
      *(float4*)(tmp + 4)  = *(const float4*)(src + 4);
      *(float4*)(tmp + 8)  = *(const float4*)(src + 8);
      *(float4*)(tmp + 12) = *(const float4*)(src + 12);
#pragma unroll
      for (int r = 0; r < 16; ++r) sV[ih + r][c] = tmp[r];
    }
    // stage A[i][w] from e[b][h][w][i]
#pragma unroll
    for (int p = 0; p < 4; ++p) {
      const int idx = p * 256 + t;
      const int ww = idx >> 3, q = idx & 7;
      float4 av = *(const float4*)(
          e + (((size_t)b * kH + h) * kW + ww) * 256 + i0 + q * 4);
      sA[q * 4 + 0][ww] = av.x;
      sA[q * 4 + 1][ww] = av.y;
      sA[q * 4 + 2][ww] = av.z;
      sA[q * 4 + 3][ww] = av.w;
    }
    __syncthreads();
#pragma unroll
    for (int kk = 0; kk < 32; ++kk) {
      float a[8], bb[8];
      *(float4*)(a + 0) = *(const float4*)&sV[kk][ty * 8];
      *(float4*)(a + 4) = *(const float4*)&sV[kk][ty * 8 + 4];
      *(float4*)(bb + 0) = *(const float4*)&sA[kk][tx * 8];
      *(float4*)(bb + 4) = *(const float4*)&sA[kk][tx * 8 + 4];
#pragma unroll
      for (int ci = 0; ci < 8; ++ci)
#pragma unroll
        for (int wi = 0; wi < 8; ++wi) acc[ci][wi] = fmaf(a[ci], bb[wi], acc[ci][wi]);
    }
    __syncthreads();
  }
#pragma unroll
  for (int ci = 0; ci < 8; ++ci) {
    const int c = m0 + ty * 8 + ci;
    float* dst = out + (((size_t)b * kC + c) * kH + h) * kW + tx * 8;
    float4 o0 = {acc[ci][0], acc[ci][1], acc[ci][2], acc[ci][3]};
    float4 o1 = {acc[ci][4], acc[ci][5], acc[ci][6], acc[ci][7]};
    *(float4*)(dst + 0) = o0;
    *(float4*)(dst + 4) = o1;
  }
}

// ---------------- col aggregation: out[b][c][h][w] += sum_j a_col[j][h,w] * v[b][c][j][w] ----
// block: (b, c-tile 64, h-tile 64, w-tile 4); per-thread 4x4x(4w) micro
__global__ __launch_bounds__(256) void colagg_kernel(
    const float* __restrict__ qkv, const float* __restrict__ e,
    float* __restrict__ out) {
  __shared__ float sV[64][17][4];   // [c][j][w], j-dim padded 16->17
  __shared__ float sA[16][64][4];   // [j][h][w]
  const int w0 = blockIdx.x * 4;
  const int h0 = blockIdx.y * 64;
  const int bz = blockIdx.z;
  const int b = bz >> 3;
  const int c0 = (bz & 7) * 64;
  const int t = threadIdx.x;
  const int th = t & 15, tc = t >> 4;
  float4 acc[4][4];
#pragma unroll
  for (int ci = 0; ci < 4; ++ci)
#pragma unroll
    for (int hi = 0; hi < 4; ++hi) acc[ci][hi] = make_float4(0.f, 0.f, 0.f, 0.f);

  for (int j0 = 0; j0 < kH; j0 += 16) {
    // stage V: sV[c][j][0..3] = v[b][c0+c][j0+j][w0..w0+3]
#pragma unroll
    for (int p = 0; p < 4; ++p) {
      const int idx = p * 256 + t;        // 0..1023
      const int cc = idx >> 4, jj = idx & 15;
      float4 vv = *(const float4*)(
          qkv + ((size_t)b * kO + 128 + c0 + cc) * kL + (j0 + jj) * kW + w0);
      *(float4*)&sV[cc][jj][0] = vv;
    }
    // stage A: sA[j][h][w] = e[b][h0+h][w0+w][128 + j0 + j]
#pragma unroll
    for (int p = 0; p < 4; ++p) {
      const int idx = p * 256 + t;        // 0..1023
      const int wwi = idx & 3, hh = (idx >> 2) & 63, j4 = idx >> 8;
      float4 av = *(const float4*)(
          e + (((size_t)b * kH + h0 + hh) * kW + w0 + wwi) * 256 + 128 + j0 + j4 * 4);
      sA[j4 * 4 + 0][hh][wwi] = av.x;
      sA[j4 * 4 + 1][hh][wwi] = av.y;
      sA[j4 * 4 + 2][hh][wwi] = av.z;
      sA[j4 * 4 + 3][hh][wwi] = av.w;
    }
    __syncthreads();
#pragma unroll
    for (int jj = 0; jj < 16; ++jj) {
      float4 vv[4], aa[4];
#pragma unroll
      for (int ci = 0; ci < 4; ++ci) vv[ci] = *(const float4*)&sV[tc + 16 * ci][jj][0];
#pragma unroll
      for (int hi = 0; hi < 4; ++hi) aa[hi] = *(const float4*)&sA[jj][th + 16 * hi][0];
#pragma unroll
      for (int ci = 0; ci < 4; ++ci)
#pragma unroll
        for (int hi = 0; hi < 4; ++hi) {
          acc[ci][hi].x = fmaf(vv[ci].x, aa[hi].x, acc[ci][hi].x);
          acc[ci][hi].y = fmaf(vv[ci].y, aa[hi].y, acc[ci][hi].y);
          acc[ci][hi].z = fmaf(vv[ci].z, aa[hi].z, acc[ci][hi].z);
          acc[ci][hi].w = fmaf(vv[ci].w, aa[hi].w, acc[ci][hi].w);
        }
    }
    __syncthreads();
  }
#pragma unroll
  for (int ci = 0; ci < 4; ++ci)
#pragma unroll
    for (int hi = 0; hi < 4; ++hi) {
      const int c = c0 + tc + 16 * ci;
      const int h = h0 + th + 16 * hi;
      float4* dst = reinterpret_cast<float4*>(
          out + (((size_t)b * kC + c) * kH + h) * kW + w0);
      float4 cur = *dst;
      cur.x += acc[ci][hi].x;
      cur.y += acc[ci][hi].y;
      cur.z += acc[ci][hi].z;
      cur.w += acc[ci][hi].w;
      *dst = cur;
    }
}

extern "C" void kernel_launch(void* const* d_in, const int* in_sizes, int n_in,
                              void* d_out, int out_size, void* d_ws, size_t ws_size,
                              hipStream_t stream) {
  (void)in_sizes; (void)n_in; (void)out_size; (void)ws_size;
  const float* x  = (const float*)d_in[0];
  const float* Wq = (const float*)d_in[1];
  const float* bq = (const float*)d_in[2];
  const float* Wk = (const float*)d_in[3];
  const float* bk = (const float*)d_in[4];
  const float* Wv = (const float*)d_in[5];
  const float* bv = (const float*)d_in[6];
  float* out = (float*)d_out;
  float* ws  = (float*)d_ws;

  float* Wall = ws + OFF_WALL;
  float* ball = ws + OFF_BALL;
  float* qkv  = ws + OFF_QKV;
  float* e    = ws + OFF_E;

  pack_w<<<dim3(kO), dim3(256), 0, stream>>>(Wq, bq, Wk, bk, Wv, bv, Wall, ball);
  proj_gemm<<<dim3(kL / 128, kO / 128, kB), dim3(256), 0, stream>>>(x, Wall, ball, qkv);
  erow_kernel<<<dim3(kB * kH), dim3(256), 0, stream>>>(qkv, e);
  ecol_kernel<<<dim3(kB * kW), dim3(256), 0, stream>>>(qkv, e);
  softmax_kernel<<<dim3(kB * kH * kW / 4), dim3(256), 0, stream>>>(e);
  rowagg_kernel<<<dim3(kC / 128, kB * kH), dim3(256), 0, stream>>>(qkv, e, out);
  colagg_kernel<<<dim3(kW / 4, kH / 64, kB * 8), dim3(256), 0, stream>>>(qkv, e, out);
}

// Round 2
// 982.904 us; speedup vs baseline: 1.2463x; 1.2463x over previous
//
#include <hip/hip_runtime.h>
#include <hip/hip_bf16.h>

namespace {
constexpr int kB = 4;
constexpr int kC = 512;
constexpr int kH = 128;
constexpr int kW = 128;
constexpr int kCQK = 64;
constexpr int kL = kH * kW;   // 16384
constexpr int kO = 640;       // rows: [0,64)=Wq, [64,128)=Wk, [128,640)=Wv

// workspace layout (float offsets)
constexpr size_t OFF_WALL = 0;                          // holds wpk: 640*512*2 bf16 = 327680 floats
constexpr size_t OFF_BALL = (size_t)kO * kC;            // 640
constexpr size_t OFF_QKV  = OFF_BALL + kO;              // B*640*L fp32
constexpr size_t OFF_E    = OFF_QKV + (size_t)kB * kO * kL;  // B*H*W*256 fp32; x_pk (32MB bf16) aliases the front of this
constexpr size_t WS_FLOATS = OFF_E + (size_t)kB * kH * kW * 256;

typedef __attribute__((ext_vector_type(8))) short bf16x8;
typedef __attribute__((ext_vector_type(4))) float f32x4;

__device__ __forceinline__ unsigned short f32_to_bf16_rn(float f) {
  unsigned u = __float_as_uint(f);
  unsigned r = (u + 0x7FFFu + ((u >> 16) & 1u)) >> 16;
  return (unsigned short)r;
}
__device__ __forceinline__ float bf16_to_f32(unsigned short h) {
  return __uint_as_float(((unsigned)h) << 16);
}
}

// ---------------- pack W/bias into bf16 hi/lo planes [640][512] ----------------
__global__ __launch_bounds__(256) void pack_w(
    const float* __restrict__ Wq, const float* __restrict__ bq,
    const float* __restrict__ Wk, const float* __restrict__ bk,
    const float* __restrict__ Wv, const float* __restrict__ bv,
    short* __restrict__ wpk, float* __restrict__ ball) {
  const int r = blockIdx.x;      // 0..639
  const int t = threadIdx.x;     // 256
  const float* src;
  if (r < 64) {
    src = Wq + (size_t)r * kC;
    if (t == 0) ball[r] = bq[r];
  } else if (r < 128) {
    src = Wk + (size_t)(r - 64) * kC;
    if (t == 0) ball[r] = bk[r - 64];
  } else {
    src = Wv + (size_t)(r - 128) * kC;
    if (t == 0) ball[r] = bv[r - 128];
  }
#pragma unroll
  for (int p = 0; p < 2; ++p) {
    const int c = p * 256 + t;
    const float v = src[c];
    const unsigned short h = f32_to_bf16_rn(v);
    const unsigned short l = f32_to_bf16_rn(v - bf16_to_f32(h));
    wpk[(size_t)r * kC + c] = (short)h;
    wpk[(size_t)kO * kC + (size_t)r * kC + c] = (short)l;
  }
}

// ---------------- pack x (one batch): fp32 [c][l] -> bf16 hi/lo [l][c] ----------------
// grid (256 l-tiles, 8 c-tiles), 64x64 tiles via LDS
__global__ __launch_bounds__(256) void pack_x(
    const float* __restrict__ x, short* __restrict__ xpk, int b) {
  __shared__ float sT[64][65];
  const int l0 = blockIdx.x * 64;
  const int c0 = blockIdx.y * 64;
  const int t = threadIdx.x;
  const float* xb = x + (size_t)b * kC * kL;
#pragma unroll
  for (int p = 0; p < 4; ++p) {
    const int ch = p * 256 + t;         // 0..1023 : 64c x 16 l4-chunks
    const int c = ch >> 4, l4 = (ch & 15) * 4;
    float4 v = *(const float4*)(xb + (size_t)(c0 + c) * kL + l0 + l4);
    sT[c][l4 + 0] = v.x; sT[c][l4 + 1] = v.y; sT[c][l4 + 2] = v.z; sT[c][l4 + 3] = v.w;
  }
  __syncthreads();
#pragma unroll
  for (int p = 0; p < 2; ++p) {
    const int ch = p * 256 + t;         // 0..511 : 64l x 8 cg-chunks
    const int l = ch >> 3, cg = ch & 7;
    short hi[8], lo[8];
#pragma unroll
    for (int j = 0; j < 8; ++j) {
      const float v = sT[cg * 8 + j][l];
      const unsigned short h = f32_to_bf16_rn(v);
      hi[j] = (short)h;
      lo[j] = (short)f32_to_bf16_rn(v - bf16_to_f32(h));
    }
    short* dh = xpk + (size_t)(l0 + l) * kC + c0 + cg * 8;
    *(bf16x8*)dh = *(bf16x8*)hi;
    *(bf16x8*)(dh + (size_t)kL * kC) = *(bf16x8*)lo;
  }
}

// ---------------- projection GEMM via bf16 MFMA, split precision ----------------
// qkv[b][m][l] = sum_c W[m][c] * x[c][l] + ball[m]
// BM=128, BN=128, BK=64; 4 waves (2x2), each 64x64 = 4x4 frags of 16x16x32.
// m-tile 0 (q,k): 3-pass (hh + h*lo(x) + lo(W)*h). m-tiles 1..4 (v): 2-pass (hh + lo(W)*h).
__global__ __launch_bounds__(256, 2) void proj_mfma(
    const short* __restrict__ xpk, const short* __restrict__ wpk,
    const float* __restrict__ ball, float* __restrict__ qkv, int b) {
  __shared__ short A_h[128 * 64];
  __shared__ short A_l[128 * 64];
  __shared__ short B_h[128 * 64];
  __shared__ short B_l[128 * 64];
  const int mt = blockIdx.x;          // 0..4  (m innermost: consecutive blocks share B tile)
  const int n0 = blockIdx.y * 128;    // 0..127 tiles
  const int m0 = mt * 128;
  const bool qk = (mt == 0);
  const int t = threadIdx.x;
  const int wid = t >> 6, lane = t & 63;
  const int wr = wid >> 1, wc = wid & 1;
  const int lr = lane & 15, lg = lane >> 4;

  f32x4 acc[4][4];
#pragma unroll
  for (int i = 0; i < 4; ++i)
#pragma unroll
    for (int j = 0; j < 4; ++j) acc[i][j] = (f32x4)(0.f);

  for (int kt = 0; kt < 8; ++kt) {
    const int k0 = kt * 64;
    // ---- stage A (W) hi+lo ----
#pragma unroll
    for (int p = 0; p < 4; ++p) {
      const int ch = p * 256 + t;       // 1024 chunks of 16B
      const int row = ch >> 3, kg = ch & 7;
      const short* src = wpk + (size_t)(m0 + row) * kC + k0 + kg * 8;
      const int off = row * 64 + ((kg ^ (row & 7)) << 3);
      *(bf16x8*)&A_h[off] = *(const bf16x8*)src;
      *(bf16x8*)&A_l[off] = *(const bf16x8*)(src + (size_t)kO * kC);
    }
    // ---- stage B (x) hi (+ lo for qk tile) ----
#pragma unroll
    for (int p = 0; p < 4; ++p) {
      const int ch = p * 256 + t;
      const int row = ch >> 3, kg = ch & 7;
      const short* src = xpk + (size_t)(n0 + row) * kC + k0 + kg * 8;
      const int off = row * 64 + ((kg ^ (row & 7)) << 3);
      *(bf16x8*)&B_h[off] = *(const bf16x8*)src;
      if (qk) *(bf16x8*)&B_l[off] = *(const bf16x8*)(src + (size_t)kL * kC);
    }
    __syncthreads();
#pragma unroll
    for (int ks = 0; ks < 2; ++ks) {
      bf16x8 ah[4], al[4], bh[4], bl[4];
#pragma unroll
      for (int mf = 0; mf < 4; ++mf) {
        const int row = wr * 64 + mf * 16 + lr;
        const int kg = ks * 4 + lg;
        const int off = row * 64 + ((kg ^ (row & 7)) << 3);
        ah[mf] = *(const bf16x8*)&A_h[off];
        al[mf] = *(const bf16x8*)&A_l[off];
      }
#pragma unroll
      for (int nf = 0; nf < 4; ++nf) {
        const int row = wc * 64 + nf * 16 + lr;
        const int kg = ks * 4 + lg;
        const int off = row * 64 + ((kg ^ (row & 7)) << 3);
        bh[nf] = *(const bf16x8*)&B_h[off];
        if (qk) bl[nf] = *(const bf16x8*)&B_l[off];
      }
#pragma unroll
      for (int mf = 0; mf < 4; ++mf)
#pragma unroll
        for (int nf = 0; nf < 4; ++nf) {
          acc[mf][nf] = __builtin_amdgcn_mfma_f32_16x16x32_bf16(
              ah[mf], bh[nf], acc[mf][nf], 0, 0, 0);
          acc[mf][nf] = __builtin_amdgcn_mfma_f32_16x16x32_bf16(
              al[mf], bh[nf], acc[mf][nf], 0, 0, 0);
          if (qk)
            acc[mf][nf] = __builtin_amdgcn_mfma_f32_16x16x32_bf16(
                ah[mf], bl[nf], acc[mf][nf], 0, 0, 0);
        }
    }
    __syncthreads();
  }
  // ---- epilogue: D row = 4*lg + r, col = lr ----
#pragma unroll
  for (int mf = 0; mf < 4; ++mf) {
#pragma unroll
    for (int r = 0; r < 4; ++r) {
      const int m = m0 + wr * 64 + mf * 16 + lg * 4 + r;
      const float bias = ball[m];
      float* dst = qkv + ((size_t)b * kO + m) * kL + n0 + wc * 64;
#pragma unroll
      for (int nf = 0; nf < 4; ++nf) {
        dst[nf * 16 + lr] = acc[mf][nf][r] + bias;
      }
    }
  }
}

// ---------------- e_row: e[b][h][w][i] = sum_c q[b,c,h,w] * k[b,c,h,i] ----------------
__global__ __launch_bounds__(256) void erow_kernel(
    const float* __restrict__ qkv, float* __restrict__ e) {
  __shared__ float sQ[32][128];   // [c][w]
  __shared__ float sK[32][128];   // [c][i]
  const int bh = blockIdx.x;
  const int b = bh >> 7, h = bh & 127;
  const int t = threadIdx.x;
  const int tx = t & 15, ty = t >> 4;
  float acc[8][8];
#pragma unroll
  for (int i = 0; i < 8; ++i)
#pragma unroll
    for (int j = 0; j < 8; ++j) acc[i][j] = 0.f;

  for (int k0 = 0; k0 < kCQK; k0 += 32) {
#pragma unroll
    for (int p = 0; p < 4; ++p) {
      const int idx = p * 256 + t;
      const int cc = idx >> 5, w4 = (idx & 31) * 4;
      const size_t base = ((size_t)b * kO + k0 + cc) * kL + h * kW + w4;
      *(float4*)&sQ[cc][w4] = *(const float4*)(qkv + base);
      *(float4*)&sK[cc][w4] = *(const float4*)(qkv + base + (size_t)64 * kL);
    }
    __syncthreads();
#pragma unroll
    for (int kk = 0; kk < 32; ++kk) {
      float a[8], bb[8];
      *(float4*)(a + 0) = *(const float4*)&sQ[kk][ty * 8];
      *(float4*)(a + 4) = *(const float4*)&sQ[kk][ty * 8 + 4];
      *(float4*)(bb + 0) = *(const float4*)&sK[kk][tx * 8];
      *(float4*)(bb + 4) = *(const float4*)&sK[kk][tx * 8 + 4];
#pragma unroll
      for (int wi = 0; wi < 8; ++wi)
#pragma unroll
        for (int ii = 0; ii < 8; ++ii) acc[wi][ii] = fmaf(a[wi], bb[ii], acc[wi][ii]);
    }
    __syncthreads();
  }
#pragma unroll
  for (int wi = 0; wi < 8; ++wi) {
    const int w = ty * 8 + wi;
    float* dst = e + (((size_t)b * kH + h) * kW + w) * 256 + tx * 8;
    float4 o0 = {acc[wi][0], acc[wi][1], acc[wi][2], acc[wi][3]};
    float4 o1 = {acc[wi][4], acc[wi][5], acc[wi][6], acc[wi][7]};
    *(float4*)(dst + 0) = o0;
    *(float4*)(dst + 4) = o1;
  }
}

// ---------------- e_col: e[b][h][w][128+j] = sum_c q[b,c,h,w]*k[b,c,j,w]; diag -> -inf ----
__global__ __launch_bounds__(256) void ecol_kernel(
    const float* __restrict__ qkv, float* __restrict__ e) {
  __shared__ float sQ[32][128];   // [c][h]
  __shared__ float sK[32][128];   // [c][j]
  const int bw = blockIdx.x;
  const int b = bw >> 7, w = bw & 127;
  const int t = threadIdx.x;
  const int tx = t & 15, ty = t >> 4;
  float acc[8][8];
#pragma unroll
  for (int i = 0; i < 8; ++i)
#pragma unroll
    for (int j = 0; j < 8; ++j) acc[i][j] = 0.f;

  for (int k0 = 0; k0 < kCQK; k0 += 32) {
#pragma unroll
    for (int p = 0; p < 16; ++p) {
      const int idx = p * 256 + t;          // 0..4095
      const int cc = idx >> 7, hh = idx & 127;
      const size_t base = ((size_t)b * kO + k0 + cc) * kL + hh * kW + w;
      sQ[cc][hh] = qkv[base];
      sK[cc][hh] = qkv[base + (size_t)64 * kL];
    }
    __syncthreads();
#pragma unroll
    for (int kk = 0; kk < 32; ++kk) {
      float a[8], bb[8];
      *(float4*)(a + 0) = *(const float4*)&sQ[kk][ty * 8];
      *(float4*)(a + 4) = *(const float4*)&sQ[kk][ty * 8 + 4];
      *(float4*)(bb + 0) = *(const float4*)&sK[kk][tx * 8];
      *(float4*)(bb + 4) = *(const float4*)&sK[kk][tx * 8 + 4];
#pragma unroll
      for (int hi = 0; hi < 8; ++hi)
#pragma unroll
        for (int ji = 0; ji < 8; ++ji) acc[hi][ji] = fmaf(a[hi], bb[ji], acc[hi][ji]);
    }
    __syncthreads();
  }
  const float NEG_INF = __int_as_float(0xff800000);
#pragma unroll
  for (int hi = 0; hi < 8; ++hi) {
    const int h = ty * 8 + hi;
    float vals[8];
#pragma unroll
    for (int ji = 0; ji < 8; ++ji) {
      const int j = tx * 8 + ji;
      vals[ji] = (j == h) ? NEG_INF : acc[hi][ji];
    }
    float* dst = e + (((size_t)b * kH + h) * kW + w) * 256 + 128 + tx * 8;
    float4 o0 = {vals[0], vals[1], vals[2], vals[3]};
    float4 o1 = {vals[4], vals[5], vals[6], vals[7]};
    *(float4*)(dst + 0) = o0;
    *(float4*)(dst + 4) = o1;
  }
}

// ---------------- softmax over the 256 contiguous scores per pixel ----------------
__global__ __launch_bounds__(256) void softmax_kernel(float* __restrict__ e) {
  const int t = threadIdx.x;
  const int wv = t >> 6, lane = t & 63;
  const size_t pix = (size_t)blockIdx.x * 4 + wv;
  float* p = e + pix * 256 + lane * 4;
  float4 v = *(const float4*)p;
  float m = fmaxf(fmaxf(v.x, v.y), fmaxf(v.z, v.w));
#pragma unroll
  for (int off = 32; off > 0; off >>= 1) m = fmaxf(m, __shfl_xor(m, off, 64));
  float e0 = expf(v.x - m), e1 = expf(v.y - m), e2 = expf(v.z - m), e3 = expf(v.w - m);
  float s = e0 + e1 + e2 + e3;
#pragma unroll
  for (int off = 32; off > 0; off >>= 1) s += __shfl_xor(s, off, 64);
  const float inv = 1.0f / s;
  float4 o = {e0 * inv, e1 * inv, e2 * inv, e3 * inv};
  *(float4*)p = o;
}

// ---------------- row aggregation: out[b][c][h][w] = sum_i a_row[i][w] * v[b][c][h][i] ----
__global__ __launch_bounds__(256) void rowagg_kernel(
    const float* __restrict__ qkv, const float* __restrict__ e,
    float* __restrict__ out) {
  __shared__ float sV[32][132];   // [i][c] (+4 pad)
  __shared__ float sA[32][132];   // [i][w]
  const int bh = blockIdx.y;
  const int b = bh >> 7, h = bh & 127;
  const int m0 = blockIdx.x * 128;
  const int t = threadIdx.x;
  const int tx = t & 15, ty = t >> 4;
  float acc[8][8];
#pragma unroll
  for (int i = 0; i < 8; ++i)
#pragma unroll
    for (int j = 0; j < 8; ++j) acc[i][j] = 0.f;

  for (int i0 = 0; i0 < kW; i0 += 32) {
    {
      const int c = t >> 1, ih = (t & 1) * 16;
      const float* src =
          qkv + ((size_t)b * kO + 128 + m0 + c) * kL + h * kW + i0 + ih;
      float tmp[16];
      *(float4*)(tmp + 0)  = *(const float4*)(src + 0);
      *(float4*)(tmp + 4)  = *(const float4*)(src + 4);
      *(float4*)(tmp + 8)  = *(const float4*)(src + 8);
      *(float4*)(tmp + 12) = *(const float4*)(src + 12);
#pragma unroll
      for (int r = 0; r < 16; ++r) sV[ih + r][c] = tmp[r];
    }
#pragma unroll
    for (int p = 0; p < 4; ++p) {
      const int idx = p * 256 + t;
      const int ww = idx >> 3, q = idx & 7;
      float4 av = *(const float4*)(
          e + (((size_t)b * kH + h) * kW + ww) * 256 + i0 + q * 4);
      sA[q * 4 + 0][ww] = av.x;
      sA[q * 4 + 1][ww] = av.y;
      sA[q * 4 + 2][ww] = av.z;
      sA[q * 4 + 3][ww] = av.w;
    }
    __syncthreads();
#pragma unroll
    for (int kk = 0; kk < 32; ++kk) {
      float a[8], bb[8];
      *(float4*)(a + 0) = *(const float4*)&sV[kk][ty * 8];
      *(float4*)(a + 4) = *(const float4*)&sV[kk][ty * 8 + 4];
      *(float4*)(bb + 0) = *(const float4*)&sA[kk][tx * 8];
      *(float4*)(bb + 4) = *(const float4*)&sA[kk][tx * 8 + 4];
#pragma unroll
      for (int ci = 0; ci < 8; ++ci)
#pragma unroll
        for (int wi = 0; wi < 8; ++wi) acc[ci][wi] = fmaf(a[ci], bb[wi], acc[ci][wi]);
    }
    __syncthreads();
  }
#pragma unroll
  for (int ci = 0; ci < 8; ++ci) {
    const int c = m0 + ty * 8 + ci;
    float* dst = out + (((size_t)b * kC + c) * kH + h) * kW + tx * 8;
    float4 o0 = {acc[ci][0], acc[ci][1], acc[ci][2], acc[ci][3]};
    float4 o1 = {acc[ci][4], acc[ci][5], acc[ci][6], acc[ci][7]};
    *(float4*)(dst + 0) = o0;
    *(float4*)(dst + 4) = o1;
  }
}

// ---------------- col aggregation: out[b][c][h][w] += sum_j a_col[j][h,w] * v[b][c][j][w] ----
__global__ __launch_bounds__(256) void colagg_kernel(
    const float* __restrict__ qkv, const float* __restrict__ e,
    float* __restrict__ out) {
  __shared__ float sV[64][17][4];   // [c][j][w], j-dim padded 16->17
  __shared__ float sA[16][64][4];   // [j][h][w]
  const int w0 = blockIdx.x * 4;
  const int h0 = blockIdx.y * 64;
  const int bz = blockIdx.z;
  const int b = bz >> 3;
  const int c0 = (bz & 7) * 64;
  const int t = threadIdx.x;
  const int th = t & 15, tc = t >> 4;
  float4 acc[4][4];
#pragma unroll
  for (int ci = 0; ci < 4; ++ci)
#pragma unroll
    for (int hi = 0; hi < 4; ++hi) acc[ci][hi] = make_float4(0.f, 0.f, 0.f, 0.f);

  for (int j0 = 0; j0 < kH; j0 += 16) {
#pragma unroll
    for (int p = 0; p < 4; ++p) {
      const int idx = p * 256 + t;        // 0..1023
      const int cc = idx >> 4, jj = idx & 15;
      float4 vv = *(const float4*)(
          qkv + ((size_t)b * kO + 128 + c0 + cc) * kL + (j0 + jj) * kW + w0);
      *(float4*)&sV[cc][jj][0] = vv;
    }
#pragma unroll
    for (int p = 0; p < 4; ++p) {
      const int idx = p * 256 + t;        // 0..1023
      const int wwi = idx & 3, hh = (idx >> 2) & 63, j4 = idx >> 8;
      float4 av = *(const float4*)(
          e + (((size_t)b * kH + h0 + hh) * kW + w0 + wwi) * 256 + 128 + j0 + j4 * 4);
      sA[j4 * 4 + 0][hh][wwi] = av.x;
      sA[j4 * 4 + 1][hh][wwi] = av.y;
      sA[j4 * 4 + 2][hh][wwi] = av.z;
      sA[j4 * 4 + 3][hh][wwi] = av.w;
    }
    __syncthreads();
#pragma unroll
    for (int jj = 0; jj < 16; ++jj) {
      float4 vv[4], aa[4];
#pragma unroll
      for (int ci = 0; ci < 4; ++ci) vv[ci] = *(const float4*)&sV[tc + 16 * ci][jj][0];
#pragma unroll
      for (int hi = 0; hi < 4; ++hi) aa[hi] = *(const float4*)&sA[jj][th + 16 * hi][0];
#pragma unroll
      for (int ci = 0; ci < 4; ++ci)
#pragma unroll
        for (int hi = 0; hi < 4; ++hi) {
          acc[ci][hi].x = fmaf(vv[ci].x, aa[hi].x, acc[ci][hi].x);
          acc[ci][hi].y = fmaf(vv[ci].y, aa[hi].y, acc[ci][hi].y);
          acc[ci][hi].z = fmaf(vv[ci].z, aa[hi].z, acc[ci][hi].z);
          acc[ci][hi].w = fmaf(vv[ci].w, aa[hi].w, acc[ci][hi].w);
        }
    }
    __syncthreads();
  }
#pragma unroll
  for (int ci = 0; ci < 4; ++ci)
#pragma unroll
    for (int hi = 0; hi < 4; ++hi) {
      const int c = c0 + tc + 16 * ci;
      const int h = h0 + th + 16 * hi;
      float4* dst = reinterpret_cast<float4*>(
          out + (((size_t)b * kC + c) * kH + h) * kW + w0);
      float4 cur = *dst;
      cur.x += acc[ci][hi].x;
      cur.y += acc[ci][hi].y;
      cur.z += acc[ci][hi].z;
      cur.w += acc[ci][hi].w;
      *dst = cur;
    }
}

extern "C" void kernel_launch(void* const* d_in, const int* in_sizes, int n_in,
                              void* d_out, int out_size, void* d_ws, size_t ws_size,
                              hipStream_t stream) {
  (void)in_sizes; (void)n_in; (void)out_size; (void)ws_size;
  const float* x  = (const float*)d_in[0];
  const float* Wq = (const float*)d_in[1];
  const float* bq = (const float*)d_in[2];
  const float* Wk = (const float*)d_in[3];
  const float* bk = (const float*)d_in[4];
  const float* Wv = (const float*)d_in[5];
  const float* bv = (const float*)d_in[6];
  float* out = (float*)d_out;
  float* ws  = (float*)d_ws;

  short* wpk = (short*)(ws + OFF_WALL);
  float* ball = ws + OFF_BALL;
  float* qkv  = ws + OFF_QKV;
  float* e    = ws + OFF_E;
  short* xpk  = (short*)(ws + OFF_E);   // 32 MB, aliases e (e written later)

  pack_w<<<dim3(kO), dim3(256), 0, stream>>>(Wq, bq, Wk, bk, Wv, bv, wpk, ball);
  for (int b = 0; b < kB; ++b) {
    pack_x<<<dim3(kL / 64, kC / 64), dim3(256), 0, stream>>>(x, xpk, b);
    proj_mfma<<<dim3(5, kL / 128), dim3(256), 0, stream>>>(xpk, wpk, ball, qkv, b);
  }
  erow_kernel<<<dim3(kB * kH), dim3(256), 0, stream>>>(qkv, e);
  ecol_kernel<<<dim3(kB * kW), dim3(256), 0, stream>>>(qkv, e);
  softmax_kernel<<<dim3(kB * kH * kW / 4), dim3(256), 0, stream>>>(e);
  rowagg_kernel<<<dim3(kC / 128, kB * kH), dim3(256), 0, stream>>>(qkv, e, out);
  colagg_kernel<<<dim3(kW / 4, kH / 64, kB * 8), dim3(256), 0, stream>>>(qkv, e, out);
}

// Round 3
// 817.337 us; speedup vs baseline: 1.4987x; 1.2026x over previous
//
#include <hip/hip_runtime.h>
#include <hip/hip_bf16.h>

namespace {
constexpr int kB = 4;
constexpr int kC = 512;
constexpr int kH = 128;
constexpr int kW = 128;
constexpr int kCQK = 64;
constexpr int kL = kH * kW;   // 16384
constexpr int kO = 640;       // rows: [0,64)=Wq, [64,128)=Wk, [128,640)=Wv

// workspace layout (float offsets)
constexpr size_t OFF_WALL = 0;                          // holds wpk: 640*512*2 bf16 = 327680 floats
constexpr size_t OFF_BALL = (size_t)kO * kC;            // 640
constexpr size_t OFF_QKV  = OFF_BALL + kO;              // B*640*L fp32
constexpr size_t OFF_E    = OFF_QKV + (size_t)kB * kO * kL;  // B*H*W*256 fp32; x_pk (32MB bf16) aliases the front of this
constexpr size_t WS_FLOATS = OFF_E + (size_t)kB * kH * kW * 256;

typedef __attribute__((ext_vector_type(8))) short bf16x8;
typedef __attribute__((ext_vector_type(4))) float f32x4;

__device__ __forceinline__ unsigned short f32_to_bf16_rn(float f) {
  unsigned u = __float_as_uint(f);
  unsigned r = (u + 0x7FFFu + ((u >> 16) & 1u)) >> 16;
  return (unsigned short)r;
}
__device__ __forceinline__ float bf16_to_f32(unsigned short h) {
  return __uint_as_float(((unsigned)h) << 16);
}
}

// ---------------- pack W/bias into bf16 hi/lo planes [640][512] ----------------
__global__ __launch_bounds__(256) void pack_w(
    const float* __restrict__ Wq, const float* __restrict__ bq,
    const float* __restrict__ Wk, const float* __restrict__ bk,
    const float* __restrict__ Wv, const float* __restrict__ bv,
    short* __restrict__ wpk, float* __restrict__ ball) {
  const int r = blockIdx.x;      // 0..639
  const int t = threadIdx.x;     // 256
  const float* src;
  if (r < 64) {
    src = Wq + (size_t)r * kC;
    if (t == 0) ball[r] = bq[r];
  } else if (r < 128) {
    src = Wk + (size_t)(r - 64) * kC;
    if (t == 0) ball[r] = bk[r - 64];
  } else {
    src = Wv + (size_t)(r - 128) * kC;
    if (t == 0) ball[r] = bv[r - 128];
  }
#pragma unroll
  for (int p = 0; p < 2; ++p) {
    const int c = p * 256 + t;
    const float v = src[c];
    const unsigned short h = f32_to_bf16_rn(v);
    const unsigned short l = f32_to_bf16_rn(v - bf16_to_f32(h));
    wpk[(size_t)r * kC + c] = (short)h;
    wpk[(size_t)kO * kC + (size_t)r * kC + c] = (short)l;
  }
}

// ---------------- pack x (one batch): fp32 [c][l] -> bf16 hi/lo [l][c] ----------------
__global__ __launch_bounds__(256) void pack_x(
    const float* __restrict__ x, short* __restrict__ xpk, int b) {
  __shared__ float sT[64][65];
  const int l0 = blockIdx.x * 64;
  const int c0 = blockIdx.y * 64;
  const int t = threadIdx.x;
  const float* xb = x + (size_t)b * kC * kL;
#pragma unroll
  for (int p = 0; p < 4; ++p) {
    const int ch = p * 256 + t;         // 0..1023 : 64c x 16 l4-chunks
    const int c = ch >> 4, l4 = (ch & 15) * 4;
    float4 v = *(const float4*)(xb + (size_t)(c0 + c) * kL + l0 + l4);
    sT[c][l4 + 0] = v.x; sT[c][l4 + 1] = v.y; sT[c][l4 + 2] = v.z; sT[c][l4 + 3] = v.w;
  }
  __syncthreads();
#pragma unroll
  for (int p = 0; p < 2; ++p) {
    const int ch = p * 256 + t;         // 0..511 : 64l x 8 cg-chunks
    const int l = ch >> 3, cg = ch & 7;
    short hi[8], lo[8];
#pragma unroll
    for (int j = 0; j < 8; ++j) {
      const float v = sT[cg * 8 + j][l];
      const unsigned short h = f32_to_bf16_rn(v);
      hi[j] = (short)h;
      lo[j] = (short)f32_to_bf16_rn(v - bf16_to_f32(h));
    }
    short* dh = xpk + (size_t)(l0 + l) * kC + c0 + cg * 8;
    *(bf16x8*)dh = *(bf16x8*)hi;
    *(bf16x8*)(dh + (size_t)kL * kC) = *(bf16x8*)lo;
  }
}

// ---------------- projection GEMM via bf16 MFMA, split precision ----------------
__global__ __launch_bounds__(256, 2) void proj_mfma(
    const short* __restrict__ xpk, const short* __restrict__ wpk,
    const float* __restrict__ ball, float* __restrict__ qkv, int b) {
  __shared__ short A_h[128 * 64];
  __shared__ short A_l[128 * 64];
  __shared__ short B_h[128 * 64];
  __shared__ short B_l[128 * 64];
  const int mt = blockIdx.x;          // 0..4
  const int n0 = blockIdx.y * 128;
  const int m0 = mt * 128;
  const bool qk = (mt == 0);
  const int t = threadIdx.x;
  const int wid = t >> 6, lane = t & 63;
  const int wr = wid >> 1, wc = wid & 1;
  const int lr = lane & 15, lg = lane >> 4;

  f32x4 acc[4][4];
#pragma unroll
  for (int i = 0; i < 4; ++i)
#pragma unroll
    for (int j = 0; j < 4; ++j) acc[i][j] = (f32x4)(0.f);

  for (int kt = 0; kt < 8; ++kt) {
    const int k0 = kt * 64;
#pragma unroll
    for (int p = 0; p < 4; ++p) {
      const int ch = p * 256 + t;
      const int row = ch >> 3, kg = ch & 7;
      const short* src = wpk + (size_t)(m0 + row) * kC + k0 + kg * 8;
      const int off = row * 64 + ((kg ^ (row & 7)) << 3);
      *(bf16x8*)&A_h[off] = *(const bf16x8*)src;
      *(bf16x8*)&A_l[off] = *(const bf16x8*)(src + (size_t)kO * kC);
    }
#pragma unroll
    for (int p = 0; p < 4; ++p) {
      const int ch = p * 256 + t;
      const int row = ch >> 3, kg = ch & 7;
      const short* src = xpk + (size_t)(n0 + row) * kC + k0 + kg * 8;
      const int off = row * 64 + ((kg ^ (row & 7)) << 3);
      *(bf16x8*)&B_h[off] = *(const bf16x8*)src;
      if (qk) *(bf16x8*)&B_l[off] = *(const bf16x8*)(src + (size_t)kL * kC);
    }
    __syncthreads();
#pragma unroll
    for (int ks = 0; ks < 2; ++ks) {
      bf16x8 ah[4], al[4], bh[4], bl[4];
#pragma unroll
      for (int mf = 0; mf < 4; ++mf) {
        const int row = wr * 64 + mf * 16 + lr;
        const int kg = ks * 4 + lg;
        const int off = row * 64 + ((kg ^ (row & 7)) << 3);
        ah[mf] = *(const bf16x8*)&A_h[off];
        al[mf] = *(const bf16x8*)&A_l[off];
      }
#pragma unroll
      for (int nf = 0; nf < 4; ++nf) {
        const int row = wc * 64 + nf * 16 + lr;
        const int kg = ks * 4 + lg;
        const int off = row * 64 + ((kg ^ (row & 7)) << 3);
        bh[nf] = *(const bf16x8*)&B_h[off];
        if (qk) bl[nf] = *(const bf16x8*)&B_l[off];
      }
#pragma unroll
      for (int mf = 0; mf < 4; ++mf)
#pragma unroll
        for (int nf = 0; nf < 4; ++nf) {
          acc[mf][nf] = __builtin_amdgcn_mfma_f32_16x16x32_bf16(
              ah[mf], bh[nf], acc[mf][nf], 0, 0, 0);
          acc[mf][nf] = __builtin_amdgcn_mfma_f32_16x16x32_bf16(
              al[mf], bh[nf], acc[mf][nf], 0, 0, 0);
          if (qk)
            acc[mf][nf] = __builtin_amdgcn_mfma_f32_16x16x32_bf16(
                ah[mf], bl[nf], acc[mf][nf], 0, 0, 0);
        }
    }
    __syncthreads();
  }
#pragma unroll
  for (int mf = 0; mf < 4; ++mf) {
#pragma unroll
    for (int r = 0; r < 4; ++r) {
      const int m = m0 + wr * 64 + mf * 16 + lg * 4 + r;
      const float bias = ball[m];
      float* dst = qkv + ((size_t)b * kO + m) * kL + n0 + wc * 64;
#pragma unroll
      for (int nf = 0; nf < 4; ++nf) {
        dst[nf * 16 + lr] = acc[mf][nf][r] + bias;
      }
    }
  }
}

// ---------------- e_row: e[b][h][w][i] = sum_c q[b,c,h,w] * k[b,c,h,i] ----------------
__global__ __launch_bounds__(256) void erow_kernel(
    const float* __restrict__ qkv, float* __restrict__ e) {
  __shared__ float sQ[32][128];   // [c][w]
  __shared__ float sK[32][128];   // [c][i]
  const int bh = blockIdx.x;
  const int b = bh >> 7, h = bh & 127;
  const int t = threadIdx.x;
  const int tx = t & 15, ty = t >> 4;
  float acc[8][8];
#pragma unroll
  for (int i = 0; i < 8; ++i)
#pragma unroll
    for (int j = 0; j < 8; ++j) acc[i][j] = 0.f;

  for (int k0 = 0; k0 < kCQK; k0 += 32) {
#pragma unroll
    for (int p = 0; p < 4; ++p) {
      const int idx = p * 256 + t;
      const int cc = idx >> 5, w4 = (idx & 31) * 4;
      const size_t base = ((size_t)b * kO + k0 + cc) * kL + h * kW + w4;
      *(float4*)&sQ[cc][w4] = *(const float4*)(qkv + base);
      *(float4*)&sK[cc][w4] = *(const float4*)(qkv + base + (size_t)64 * kL);
    }
    __syncthreads();
#pragma unroll
    for (int kk = 0; kk < 32; ++kk) {
      float a[8], bb[8];
      *(float4*)(a + 0) = *(const float4*)&sQ[kk][ty * 8];
      *(float4*)(a + 4) = *(const float4*)&sQ[kk][ty * 8 + 4];
      *(float4*)(bb + 0) = *(const float4*)&sK[kk][tx * 8];
      *(float4*)(bb + 4) = *(const float4*)&sK[kk][tx * 8 + 4];
#pragma unroll
      for (int wi = 0; wi < 8; ++wi)
#pragma unroll
        for (int ii = 0; ii < 8; ++ii) acc[wi][ii] = fmaf(a[wi], bb[ii], acc[wi][ii]);
    }
    __syncthreads();
  }
#pragma unroll
  for (int wi = 0; wi < 8; ++wi) {
    const int w = ty * 8 + wi;
    float* dst = e + (((size_t)b * kH + h) * kW + w) * 256 + tx * 8;
    float4 o0 = {acc[wi][0], acc[wi][1], acc[wi][2], acc[wi][3]};
    float4 o1 = {acc[wi][4], acc[wi][5], acc[wi][6], acc[wi][7]};
    *(float4*)(dst + 0) = o0;
    *(float4*)(dst + 4) = o1;
  }
}

// ---------------- e_col: e[b][h][w][128+j] = sum_c q[b,c,h,w]*k[b,c,j,w]; diag -> -inf ----
__global__ __launch_bounds__(256) void ecol_kernel(
    const float* __restrict__ qkv, float* __restrict__ e) {
  __shared__ float sQ[32][128];   // [c][h]
  __shared__ float sK[32][128];   // [c][j]
  const int bw = blockIdx.x;
  const int b = bw >> 7, w = bw & 127;
  const int t = threadIdx.x;
  const int tx = t & 15, ty = t >> 4;
  float acc[8][8];
#pragma unroll
  for (int i = 0; i < 8; ++i)
#pragma unroll
    for (int j = 0; j < 8; ++j) acc[i][j] = 0.f;

  for (int k0 = 0; k0 < kCQK; k0 += 32) {
#pragma unroll
    for (int p = 0; p < 16; ++p) {
      const int idx = p * 256 + t;          // 0..4095
      const int cc = idx >> 7, hh = idx & 127;
      const size_t base = ((size_t)b * kO + k0 + cc) * kL + hh * kW + w;
      sQ[cc][hh] = qkv[base];
      sK[cc][hh] = qkv[base + (size_t)64 * kL];
    }
    __syncthreads();
#pragma unroll
    for (int kk = 0; kk < 32; ++kk) {
      float a[8], bb[8];
      *(float4*)(a + 0) = *(const float4*)&sQ[kk][ty * 8];
      *(float4*)(a + 4) = *(const float4*)&sQ[kk][ty * 8 + 4];
      *(float4*)(bb + 0) = *(const float4*)&sK[kk][tx * 8];
      *(float4*)(bb + 4) = *(const float4*)&sK[kk][tx * 8 + 4];
#pragma unroll
      for (int hi = 0; hi < 8; ++hi)
#pragma unroll
        for (int ji = 0; ji < 8; ++ji) acc[hi][ji] = fmaf(a[hi], bb[ji], acc[hi][ji]);
    }
    __syncthreads();
  }
  const float NEG_INF = __int_as_float(0xff800000);
#pragma unroll
  for (int hi = 0; hi < 8; ++hi) {
    const int h = ty * 8 + hi;
    float vals[8];
#pragma unroll
    for (int ji = 0; ji < 8; ++ji) {
      const int j = tx * 8 + ji;
      vals[ji] = (j == h) ? NEG_INF : acc[hi][ji];
    }
    float* dst = e + (((size_t)b * kH + h) * kW + w) * 256 + 128 + tx * 8;
    float4 o0 = {vals[0], vals[1], vals[2], vals[3]};
    float4 o1 = {vals[4], vals[5], vals[6], vals[7]};
    *(float4*)(dst + 0) = o0;
    *(float4*)(dst + 4) = o1;
  }
}

// ---------------- softmax over the 256 contiguous scores per pixel ----------------
__global__ __launch_bounds__(256) void softmax_kernel(float* __restrict__ e) {
  const int t = threadIdx.x;
  const int wv = t >> 6, lane = t & 63;
  const size_t pix = (size_t)blockIdx.x * 4 + wv;
  float* p = e + pix * 256 + lane * 4;
  float4 v = *(const float4*)p;
  float m = fmaxf(fmaxf(v.x, v.y), fmaxf(v.z, v.w));
#pragma unroll
  for (int off = 32; off > 0; off >>= 1) m = fmaxf(m, __shfl_xor(m, off, 64));
  float e0 = expf(v.x - m), e1 = expf(v.y - m), e2 = expf(v.z - m), e3 = expf(v.w - m);
  float s = e0 + e1 + e2 + e3;
#pragma unroll
  for (int off = 32; off > 0; off >>= 1) s += __shfl_xor(s, off, 64);
  const float inv = 1.0f / s;
  float4 o = {e0 * inv, e1 * inv, e2 * inv, e3 * inv};
  *(float4*)p = o;
}

// ---------------- row aggregation: out[b][c][h][w] = sum_i a_row[i][w] * v[b][c][h][i] ----
__global__ __launch_bounds__(256) void rowagg_kernel(
    const float* __restrict__ qkv, const float* __restrict__ e,
    float* __restrict__ out) {
  __shared__ float sV[32][132];   // [i][c] (+4 pad)
  __shared__ float sA[32][132];   // [i][w]
  const int bh = blockIdx.y;
  const int b = bh >> 7, h = bh & 127;
  const int m0 = blockIdx.x * 128;
  const int t = threadIdx.x;
  const int tx = t & 15, ty = t >> 4;
  float acc[8][8];
#pragma unroll
  for (int i = 0; i < 8; ++i)
#pragma unroll
    for (int j = 0; j < 8; ++j) acc[i][j] = 0.f;

  for (int i0 = 0; i0 < kW; i0 += 32) {
    {
      const int c = t >> 1, ih = (t & 1) * 16;
      const float* src =
          qkv + ((size_t)b * kO + 128 + m0 + c) * kL + h * kW + i0 + ih;
      float tmp[16];
      *(float4*)(tmp + 0)  = *(const float4*)(src + 0);
      *(float4*)(tmp + 4)  = *(const float4*)(src + 4);
      *(float4*)(tmp + 8)  = *(const float4*)(src + 8);
      *(float4*)(tmp + 12) = *(const float4*)(src + 12);
#pragma unroll
      for (int r = 0; r < 16; ++r) sV[ih + r][c] = tmp[r];
    }
#pragma unroll
    for (int p = 0; p < 4; ++p) {
      const int idx = p * 256 + t;
      const int ww = idx >> 3, q = idx & 7;
      float4 av = *(const float4*)(
          e + (((size_t)b * kH + h) * kW + ww) * 256 + i0 + q * 4);
      sA[q * 4 + 0][ww] = av.x;
      sA[q * 4 + 1][ww] = av.y;
      sA[q * 4 + 2][ww] = av.z;
      sA[q * 4 + 3][ww] = av.w;
    }
    __syncthreads();
#pragma unroll
    for (int kk = 0; kk < 32; ++kk) {
      float a[8], bb[8];
      *(float4*)(a + 0) = *(const float4*)&sV[kk][ty * 8];
      *(float4*)(a + 4) = *(const float4*)&sV[kk][ty * 8 + 4];
      *(float4*)(bb + 0) = *(const float4*)&sA[kk][tx * 8];
      *(float4*)(bb + 4) = *(const float4*)&sA[kk][tx * 8 + 4];
#pragma unroll
      for (int ci = 0; ci < 8; ++ci)
#pragma unroll
        for (int wi = 0; wi < 8; ++wi) acc[ci][wi] = fmaf(a[ci], bb[wi], acc[ci][wi]);
    }
    __syncthreads();
  }
#pragma unroll
  for (int ci = 0; ci < 8; ++ci) {
    const int c = m0 + ty * 8 + ci;
    float* dst = out + (((size_t)b * kC + c) * kH + h) * kW + tx * 8;
    float4 o0 = {acc[ci][0], acc[ci][1], acc[ci][2], acc[ci][3]};
    float4 o1 = {acc[ci][4], acc[ci][5], acc[ci][6], acc[ci][7]};
    *(float4*)(dst + 0) = o0;
    *(float4*)(dst + 4) = o1;
  }
}

// ---------------- col aggregation v2 ----------------
// out[b][c][h][w] += sum_j a_col[j][h][w] * v[b][c][j][w]
// Tile: c=64, h=16, w=16; j-step 8. Threads 256 = (tw 16, th 4, tc 4).
// Thread covers c = tc + 4*ci (ci 0..15), h = th*4 + hi (hi 0..3), w = tw.
// Grid: x = ct(8) + 8*ht(8)  [c fastest -> A-slice L3 reuse; V slice resident per (b,w16)],
//       y = w-tile(8), z = b(4).
__global__ __launch_bounds__(256) void colagg_kernel(
    const float* __restrict__ qkv, const float* __restrict__ e,
    float* __restrict__ out) {
  __shared__ float sV[8][16][68];   // [j][w][c] (c padded 64->68)
  __shared__ float sA[8][16][17];   // [j][w][h] (h padded 16->17)
  const int ct = blockIdx.x & 7, ht = blockIdx.x >> 3;
  const int c0 = ct * 64, h0 = ht * 16;
  const int w0 = blockIdx.y * 16;
  const int b = blockIdx.z;
  const int t = threadIdx.x;
  const int tw = t & 15, th = (t >> 4) & 3, tc = t >> 6;

  float acc[16][4];
#pragma unroll
  for (int ci = 0; ci < 16; ++ci)
#pragma unroll
    for (int hi = 0; hi < 4; ++hi) acc[ci][hi] = 0.f;

  const float* vbase = qkv + ((size_t)b * kO + 128 + c0) * kL;        // + c*kL + j*kW + w
  const float* ebase = e + (((size_t)b * kH + h0) * kW + w0) * 256;   // + h*kW*256 + w*256 + 128 + j

  // staging roles
  const int sc = t & 63;        // c for V stage (0..63)
  const int sjq = t >> 6;       // j-quad base for V stage
  const int sh = t >> 4;        // h for A stage (0..15)
  const int sw = t & 15;        // w for A stage

  for (int j0 = 0; j0 < kH; j0 += 8) {
    // ---- stage V: sV[j][w][c] = v[c0+c][j0+j][w0+w], 512 (c,j) pairs, 2/thread ----
#pragma unroll
    for (int p = 0; p < 2; ++p) {
      const int j = sjq + 4 * p;            // 0..7
      const float* src = vbase + (size_t)sc * kL + (size_t)(j0 + j) * kW + w0;
      float tmp[16];
      *(float4*)(tmp + 0)  = *(const float4*)(src + 0);
      *(float4*)(tmp + 4)  = *(const float4*)(src + 4);
      *(float4*)(tmp + 8)  = *(const float4*)(src + 8);
      *(float4*)(tmp + 12) = *(const float4*)(src + 12);
#pragma unroll
      for (int r = 0; r < 16; ++r) sV[j][r][sc] = tmp[r];
    }
    // ---- stage A: sA[j][w][h] = e[pix(h0+sh, w0+sw)][128 + j0 + j], 8 j per pixel ----
    {
      const float* src = ebase + ((size_t)sh * kW + sw) * 256 + 128 + j0;
      float a8[8];
      *(float4*)(a8 + 0) = *(const float4*)(src + 0);
      *(float4*)(a8 + 4) = *(const float4*)(src + 4);
#pragma unroll
      for (int j = 0; j < 8; ++j) sA[j][sw][sh] = a8[j];
    }
    __syncthreads();
    // ---- compute ----
#pragma unroll
    for (int j = 0; j < 8; ++j) {
      float a0 = sA[j][tw][th * 4 + 0];
      float a1 = sA[j][tw][th * 4 + 1];
      float a2 = sA[j][tw][th * 4 + 2];
      float a3 = sA[j][tw][th * 4 + 3];
#pragma unroll
      for (int ci = 0; ci < 16; ++ci) {
        const float v = sV[j][tw][tc + 4 * ci];
        acc[ci][0] = fmaf(v, a0, acc[ci][0]);
        acc[ci][1] = fmaf(v, a1, acc[ci][1]);
        acc[ci][2] = fmaf(v, a2, acc[ci][2]);
        acc[ci][3] = fmaf(v, a3, acc[ci][3]);
      }
    }
    __syncthreads();
  }
  // ---- epilogue: RMW out ----
#pragma unroll
  for (int ci = 0; ci < 16; ++ci) {
    const int c = c0 + tc + 4 * ci;
#pragma unroll
    for (int hi = 0; hi < 4; ++hi) {
      const int h = h0 + th * 4 + hi;
      float* dst = out + (((size_t)b * kC + c) * kH + h) * kW + w0 + tw;
      *dst += acc[ci][hi];
    }
  }
}

extern "C" void kernel_launch(void* const* d_in, const int* in_sizes, int n_in,
                              void* d_out, int out_size, void* d_ws, size_t ws_size,
                              hipStream_t stream) {
  (void)in_sizes; (void)n_in; (void)out_size; (void)ws_size;
  const float* x  = (const float*)d_in[0];
  const float* Wq = (const float*)d_in[1];
  const float* bq = (const float*)d_in[2];
  const float* Wk = (const float*)d_in[3];
  const float* bk = (const float*)d_in[4];
  const float* Wv = (const float*)d_in[5];
  const float* bv = (const float*)d_in[6];
  float* out = (float*)d_out;
  float* ws  = (float*)d_ws;

  short* wpk = (short*)(ws + OFF_WALL);
  float* ball = ws + OFF_BALL;
  float* qkv  = ws + OFF_QKV;
  float* e    = ws + OFF_E;
  short* xpk  = (short*)(ws + OFF_E);   // 32 MB, aliases e (e written later)

  pack_w<<<dim3(kO), dim3(256), 0, stream>>>(Wq, bq, Wk, bk, Wv, bv, wpk, ball);
  for (int b = 0; b < kB; ++b) {
    pack_x<<<dim3(kL / 64, kC / 64), dim3(256), 0, stream>>>(x, xpk, b);
    proj_mfma<<<dim3(5, kL / 128), dim3(256), 0, stream>>>(xpk, wpk, ball, qkv, b);
  }
  erow_kernel<<<dim3(kB * kH), dim3(256), 0, stream>>>(qkv, e);
  ecol_kernel<<<dim3(kB * kW), dim3(256), 0, stream>>>(qkv, e);
  softmax_kernel<<<dim3(kB * kH * kW / 4), dim3(256), 0, stream>>>(e);
  rowagg_kernel<<<dim3(kC / 128, kB * kH), dim3(256), 0, stream>>>(qkv, e, out);
  colagg_kernel<<<dim3(64, kW / 16, kB), dim3(256), 0, stream>>>(qkv, e, out);
}